// Round 1
// baseline (203.391 us; speedup 1.0000x reference)
//
#include <hip/hip_runtime.h>
#include <math.h>

#define NN 8192
#define FD 32

constexpr float POS_R2 = 0.0375f * 0.0375f;   // positive radius squared
constexpr float NEG_R2 = 0.1f * 0.1f;         // negative radius squared
constexpr float EPSF   = 1e-7f;
constexpr float POS_TH = 0.1f;
constexpr float NEG_TH = 1.4f;

// workspace layout (in floats)
#define OFF_SPTS 0                       // [NN] float4: (x,y,z,|p|^2) transformed src
#define OFF_TPTS (NN * 4)                // [NN] float4: tgt
#define OFF_SF   (NN * 8)                // [NN][FD] gathered src feats
#define OFF_TF   (NN * 8 + NN * FD)      // [NN][FD] gathered tgt feats
#define OFF_SNF  (NN * 8 + NN * FD * 2)  // [NN] src feat norms^2
#define OFF_TNF  (OFF_SNF + NN)          // [NN] tgt feat norms^2
#define OFF_MAXB (OFF_TNF + NN)          // [NN] per-row max d2f among positives (uint-ordered)
#define OFF_MINB (OFF_MAXB + NN)         // [NN] per-row min d2f among negatives
#define WS_FLOATS (OFF_MINB + NN)

// ---------------------------------------------------------------------------
// Phase 1: gather + rigid transform + norms + init reduction buffers
// ---------------------------------------------------------------------------
__global__ __launch_bounds__(256) void hcl_prep_kernel(
    const float* __restrict__ src_pcd, const float* __restrict__ tgt_pcd,
    const float* __restrict__ src_feats, const float* __restrict__ tgt_feats,
    const int* __restrict__ corr, const float* __restrict__ rot,
    const float* __restrict__ trans, float* __restrict__ ws) {
  int i = blockIdx.x * blockDim.x + threadIdx.x;
  if (i >= NN) return;
  int ci = corr[2 * i];
  int cj = corr[2 * i + 1];

  float r00 = rot[0], r01 = rot[1], r02 = rot[2];
  float r10 = rot[3], r11 = rot[4], r12 = rot[5];
  float r20 = rot[6], r21 = rot[7], r22 = rot[8];
  float t0 = trans[0], t1 = trans[1], t2 = trans[2];

  float px = src_pcd[ci * 3 + 0], py = src_pcd[ci * 3 + 1], pz = src_pcd[ci * 3 + 2];
  float qx = r00 * px + r01 * py + r02 * pz + t0;
  float qy = r10 * px + r11 * py + r12 * pz + t1;
  float qz = r20 * px + r21 * py + r22 * pz + t2;
  ((float4*)(ws + OFF_SPTS))[i] = make_float4(qx, qy, qz, qx * qx + qy * qy + qz * qz);

  float ux = tgt_pcd[cj * 3 + 0], uy = tgt_pcd[cj * 3 + 1], uz = tgt_pcd[cj * 3 + 2];
  ((float4*)(ws + OFF_TPTS))[i] = make_float4(ux, uy, uz, ux * ux + uy * uy + uz * uz);

  float ns = 0.f, nt = 0.f;
  const float4* sf = (const float4*)(src_feats + (size_t)ci * FD);
  const float4* tf = (const float4*)(tgt_feats + (size_t)cj * FD);
  float4* osf = (float4*)(ws + OFF_SF + (size_t)i * FD);
  float4* otf = (float4*)(ws + OFF_TF + (size_t)i * FD);
#pragma unroll
  for (int k = 0; k < FD / 4; ++k) {
    float4 a = sf[k];
    osf[k] = a;
    ns += a.x * a.x + a.y * a.y + a.z * a.z + a.w * a.w;
    float4 b = tf[k];
    otf[k] = b;
    nt += b.x * b.x + b.y * b.y + b.z * b.z + b.w * b.w;
  }
  ws[OFF_SNF + i] = ns;
  ws[OFF_TNF + i] = nt;
  ws[OFF_MAXB + i] = 0.0f;          // absent positives -> fp = sqrt(eps) -> relu 0, same loss
  ws[OFF_MINB + i] = __FLT_MAX__;   // absent negatives -> huge cn -> relu 0, same loss
}

// ---------------------------------------------------------------------------
// Phase 2: fused pairwise distances + masked row max/min
// Block tile: 64 rows x 64 cols, 256 threads, 4x4 per thread.
// Grid: (JSPLIT, NN/64). K-major LDS tiles so float4 fragment reads are
// conflict-free across the 16 tx lanes.
// ---------------------------------------------------------------------------
#define BI 64
#define BJ 64
#define JSPLIT 8
#define JCHUNK (NN / JSPLIT)  // 1024
#define JTILES (JCHUNK / BJ)  // 16

__global__ __launch_bounds__(256) void hcl_dist_kernel(float* __restrict__ ws) {
  __shared__ float As[FD][BI];  // k-major: As[k][row]
  __shared__ float Bs[FD][BJ];

  const int t = threadIdx.x;
  const int tx = t & 15;
  const int ty = t >> 4;
  const int i0 = blockIdx.y * BI;
  const int j0base = blockIdx.x * JCHUNK;

  // stage A (src feats) tile once, transposed to k-major
  {
    const float4* gsf = (const float4*)(ws + OFF_SF);
#pragma unroll
    for (int u = 0; u < 2; ++u) {
      int f = t + u * 256;  // 0..511
      int row = f >> 3;
      int kc = f & 7;
      float4 v = gsf[(size_t)(i0 + row) * 8 + kc];
      As[kc * 4 + 0][row] = v.x;
      As[kc * 4 + 1][row] = v.y;
      As[kc * 4 + 2][row] = v.z;
      As[kc * 4 + 3][row] = v.w;
    }
  }

  // per-thread src-side registers (constant over the j loop)
  float4 ap[4];
  float anf[4];
#pragma unroll
  for (int r = 0; r < 4; ++r) {
    ap[r] = ((const float4*)(ws + OFF_SPTS))[i0 + ty * 4 + r];
    anf[r] = ws[OFF_SNF + i0 + ty * 4 + r];
  }

  float maxd2[4], mind2[4];
#pragma unroll
  for (int r = 0; r < 4; ++r) {
    maxd2[r] = -1.0f;
    mind2[r] = __FLT_MAX__;
  }

  for (int jt = 0; jt < JTILES; ++jt) {
    const int j0 = j0base + jt * BJ;
    __syncthreads();  // protect Bs (and As on first iter) before restaging
    {
      const float4* gtf = (const float4*)(ws + OFF_TF);
#pragma unroll
      for (int u = 0; u < 2; ++u) {
        int f = t + u * 256;
        int row = f >> 3;
        int kc = f & 7;
        float4 v = gtf[(size_t)(j0 + row) * 8 + kc];
        Bs[kc * 4 + 0][row] = v.x;
        Bs[kc * 4 + 1][row] = v.y;
        Bs[kc * 4 + 2][row] = v.z;
        Bs[kc * 4 + 3][row] = v.w;
      }
    }
    __syncthreads();

    float4 bp[4];
    float bnf[4];
#pragma unroll
    for (int c = 0; c < 4; ++c) {
      bp[c] = ((const float4*)(ws + OFF_TPTS))[j0 + tx * 4 + c];
      bnf[c] = ws[OFF_TNF + j0 + tx * 4 + c];
    }

    // feature dot products (outer-product accumulation, K=32)
    float dot[4][4];
#pragma unroll
    for (int r = 0; r < 4; ++r)
#pragma unroll
      for (int c = 0; c < 4; ++c) dot[r][c] = 0.f;

#pragma unroll
    for (int k = 0; k < FD; ++k) {
      float4 a = *(const float4*)&As[k][ty * 4];
      float4 b = *(const float4*)&Bs[k][tx * 4];
      dot[0][0] += a.x * b.x; dot[0][1] += a.x * b.y; dot[0][2] += a.x * b.z; dot[0][3] += a.x * b.w;
      dot[1][0] += a.y * b.x; dot[1][1] += a.y * b.y; dot[1][2] += a.y * b.z; dot[1][3] += a.y * b.w;
      dot[2][0] += a.z * b.x; dot[2][1] += a.z * b.y; dot[2][2] += a.z * b.z; dot[2][3] += a.z * b.w;
      dot[3][0] += a.w * b.x; dot[3][1] += a.w * b.y; dot[3][2] += a.w * b.z; dot[3][3] += a.w * b.w;
    }

#pragma unroll
    for (int r = 0; r < 4; ++r) {
#pragma unroll
      for (int c = 0; c < 4; ++c) {
        float d2p = ap[r].w + bp[c].w -
                    2.f * (ap[r].x * bp[c].x + ap[r].y * bp[c].y + ap[r].z * bp[c].z);
        d2p = fmaxf(d2p, 0.f);
        float d2f = anf[r] + bnf[c] - 2.f * dot[r][c];
        bool pos = (d2p + EPSF) < POS_R2;  // sqrt(d2p+eps) < r  <=>  d2p+eps < r^2
        bool neg = (d2p + EPSF) > NEG_R2;
        if (pos) maxd2[r] = fmaxf(maxd2[r], d2f);
        if (neg) mind2[r] = fminf(mind2[r], d2f);
      }
    }
  }

  // reduce across the 16 tx lanes (contiguous in the wave), then atomic merge
#pragma unroll
  for (int r = 0; r < 4; ++r) {
    float mx = maxd2[r], mn = mind2[r];
#pragma unroll
    for (int s = 8; s >= 1; s >>= 1) {
      mx = fmaxf(mx, __shfl_down(mx, s, 16));
      mn = fminf(mn, __shfl_down(mn, s, 16));
    }
    if (tx == 0) {
      float cmx = fmaxf(mx, 0.f);  // clamp: values >= 0 so uint order == float order
      float cmn = fmaxf(mn, 0.f);
      atomicMax((unsigned int*)(ws + OFF_MAXB + i0 + ty * 4 + r), __float_as_uint(cmx));
      atomicMin((unsigned int*)(ws + OFF_MINB + i0 + ty * 4 + r), __float_as_uint(cmn));
    }
  }
}

// ---------------------------------------------------------------------------
// Phase 3: final loss reduction (single block)
// ---------------------------------------------------------------------------
__global__ __launch_bounds__(256) void hcl_loss_kernel(const float* __restrict__ ws,
                                                       float* __restrict__ out) {
  int t = threadIdx.x;
  float sp = 0.f, sn = 0.f;
  for (int i = t; i < NN; i += 256) {
    float fp = sqrtf(ws[OFF_MAXB + i] + EPSF);
    float cn = sqrtf(ws[OFF_MINB + i] + EPSF);  // FLT_MAX sentinel -> huge -> relu 0
    sp += fmaxf(fp - POS_TH, 0.f);
    sn += fmaxf(NEG_TH - cn, 0.f);
  }
  __shared__ float red[8];
#pragma unroll
  for (int s = 32; s >= 1; s >>= 1) {
    sp += __shfl_down(sp, s, 64);
    sn += __shfl_down(sn, s, 64);
  }
  int wid = t >> 6;
  if ((t & 63) == 0) {
    red[wid] = sp;
    red[4 + wid] = sn;
  }
  __syncthreads();
  if (t == 0) {
    float tsp = red[0] + red[1] + red[2] + red[3];
    float tsn = red[4] + red[5] + red[6] + red[7];
    out[0] = (tsp + tsn) / (float)NN;
  }
}

// ---------------------------------------------------------------------------
extern "C" void kernel_launch(void* const* d_in, const int* in_sizes, int n_in,
                              void* d_out, int out_size, void* d_ws, size_t ws_size,
                              hipStream_t stream) {
  const float* src_pcd = (const float*)d_in[0];
  const float* tgt_pcd = (const float*)d_in[1];
  const float* src_feats = (const float*)d_in[2];
  const float* tgt_feats = (const float*)d_in[3];
  const int* corr = (const int*)d_in[4];
  const float* rot = (const float*)d_in[5];
  const float* trans = (const float*)d_in[6];
  float* out = (float*)d_out;
  float* ws = (float*)d_ws;

  hcl_prep_kernel<<<NN / 256, 256, 0, stream>>>(src_pcd, tgt_pcd, src_feats, tgt_feats,
                                                corr, rot, trans, ws);
  hcl_dist_kernel<<<dim3(JSPLIT, NN / BI), 256, 0, stream>>>(ws);
  hcl_loss_kernel<<<1, 256, 0, stream>>>(ws, out);
}

// Round 2
// 104.847 us; speedup vs baseline: 1.9399x; 1.9399x over previous
//
#include <hip/hip_runtime.h>
#include <math.h>
#include <float.h>

#define NN 8192

typedef __bf16 bf16x8 __attribute__((ext_vector_type(8)));
typedef __bf16 bf16x4 __attribute__((ext_vector_type(4)));
typedef float f32x4 __attribute__((ext_vector_type(4)));

constexpr float POS_R2 = 0.0375f * 0.0375f;
constexpr float NEG_R2 = 0.1f * 0.1f;
constexpr float EPSF = 1e-7f;
constexpr float PRC = POS_R2 - EPSF;  // pos:  d2p < PRC
constexpr float NRC = NEG_R2 - EPSF;  // neg:  d2p > NRC
constexpr float POS_TH = 0.1f;
constexpr float NEG_TH = 1.4f;

// ws byte offsets
#define FT_OFF 0                          // bf16 [NN][32] tgt feats
#define FS2_OFF (NN * 64)                 // bf16 [NN][32] -2 * src feats
#define PSX_OFF (2 * NN * 64)             // bf16 [NN][32] src pos ext (A side)
#define PTX_OFF (3 * NN * 64)             // bf16 [NN][32] tgt pos ext (B side)
#define FNS_OFF (4 * NN * 64)             // f32 [NN] src feat |.|^2 (of rounded feats)
#define FNT_OFF (4 * NN * 64 + NN * 4)    // f32 [NN] tgt feat |.|^2
#define MAXB_OFF (4 * NN * 64 + 2 * NN * 4)
#define MINB_OFF (4 * NN * 64 + 3 * NN * 4)

// ---------------------------------------------------------------------------
// Phase 1: gather + transform + bf16 conversion + MFMA operand packing
// ---------------------------------------------------------------------------
__global__ __launch_bounds__(256) void hcl_prep(
    const float* __restrict__ src_pcd, const float* __restrict__ tgt_pcd,
    const float* __restrict__ src_feats, const float* __restrict__ tgt_feats,
    const int* __restrict__ corr, const float* __restrict__ rot,
    const float* __restrict__ trans, char* __restrict__ ws) {
  int i = blockIdx.x * 256 + threadIdx.x;
  if (i >= NN) return;
  int ci = corr[2 * i];
  int cj = corr[2 * i + 1];

  // ---- positions ----
  float r00 = rot[0], r01 = rot[1], r02 = rot[2];
  float r10 = rot[3], r11 = rot[4], r12 = rot[5];
  float r20 = rot[6], r21 = rot[7], r22 = rot[8];
  float t0 = trans[0], t1 = trans[1], t2 = trans[2];

  float px = src_pcd[ci * 3 + 0], py = src_pcd[ci * 3 + 1], pz = src_pcd[ci * 3 + 2];
  float qx = r00 * px + r01 * py + r02 * pz + t0;
  float qy = r10 * px + r11 * py + r12 * pz + t1;
  float qz = r20 * px + r21 * py + r22 * pz + t2;
  float sa = qx * qx + qy * qy + qz * qz;

  float ux = tgt_pcd[cj * 3 + 0], uy = tgt_pcd[cj * 3 + 1], uz = tgt_pcd[cj * 3 + 2];
  float sb = ux * ux + uy * uy + uz * uz;

  // hi/lo bf16 splits
  __bf16 qhx = (__bf16)qx, qhy = (__bf16)qy, qhz = (__bf16)qz;
  __bf16 qlx = (__bf16)(qx - (float)qhx);
  __bf16 qly = (__bf16)(qy - (float)qhy);
  __bf16 qlz = (__bf16)(qz - (float)qhz);
  __bf16 sah = (__bf16)sa;
  __bf16 sal = (__bf16)(sa - (float)sah);

  __bf16 uhx = (__bf16)ux, uhy = (__bf16)uy, uhz = (__bf16)uz;
  __bf16 ulx = (__bf16)(ux - (float)uhx);
  __bf16 uly = (__bf16)(uy - (float)uhy);
  __bf16 ulz = (__bf16)(uz - (float)uhz);
  __bf16 sbh = (__bf16)sb;
  __bf16 sbl = (__bf16)(sb - (float)sbh);
  // -2x of a bf16 value is exact in bf16
  __bf16 m2hx = (__bf16)(-2.f * (float)uhx), m2hy = (__bf16)(-2.f * (float)uhy),
         m2hz = (__bf16)(-2.f * (float)uhz);
  __bf16 m2lx = (__bf16)(-2.f * (float)ulx), m2ly = (__bf16)(-2.f * (float)uly),
         m2lz = (__bf16)(-2.f * (float)ulz);
  __bf16 one = (__bf16)1.0f, zero = (__bf16)0.0f;

  // PSX row (A side): [ahi(3), ahi(3), alo(3), sahi, salo, 1, 1, 0...]
  {
    bf16x8 v0, v1, vz;
    v0[0] = qhx; v0[1] = qhy; v0[2] = qhz; v0[3] = qhx; v0[4] = qhy; v0[5] = qhz;
    v0[6] = qlx; v0[7] = qly;
    v1[0] = qlz; v1[1] = sah; v1[2] = sal; v1[3] = one; v1[4] = one;
    v1[5] = zero; v1[6] = zero; v1[7] = zero;
    for (int k = 0; k < 8; ++k) vz[k] = zero;
    bf16x8* p = (bf16x8*)(ws + PSX_OFF + (size_t)i * 64);
    p[0] = v0; p[1] = v1; p[2] = vz; p[3] = vz;
  }
  // PTX row (B side): [-2bhi(3), -2blo(3), -2bhi(3), 1, 1, sbhi, sblo, 0...]
  {
    bf16x8 w0, w1, wz;
    w0[0] = m2hx; w0[1] = m2hy; w0[2] = m2hz; w0[3] = m2lx; w0[4] = m2ly; w0[5] = m2lz;
    w0[6] = m2hx; w0[7] = m2hy;
    w1[0] = m2hz; w1[1] = one; w1[2] = one; w1[3] = sbh; w1[4] = sbl;
    w1[5] = zero; w1[6] = zero; w1[7] = zero;
    for (int k = 0; k < 8; ++k) wz[k] = zero;
    bf16x8* p = (bf16x8*)(ws + PTX_OFF + (size_t)i * 64);
    p[0] = w0; p[1] = w1; p[2] = wz; p[3] = wz;
  }

  // ---- feats ----
  float fa = 0.f, fb = 0.f;
  const float4* sf = (const float4*)(src_feats + (size_t)ci * 32);
  const float4* tf = (const float4*)(tgt_feats + (size_t)cj * 32);
  bf16x4* ofs = (bf16x4*)(ws + FS2_OFF + (size_t)i * 64);
  bf16x4* oft = (bf16x4*)(ws + FT_OFF + (size_t)i * 64);
#pragma unroll
  for (int k = 0; k < 8; ++k) {
    float4 a = sf[k];
    __bf16 h0 = (__bf16)a.x, h1 = (__bf16)a.y, h2 = (__bf16)a.z, h3 = (__bf16)a.w;
    float f0 = (float)h0, f1 = (float)h1, f2 = (float)h2, f3 = (float)h3;
    fa += f0 * f0 + f1 * f1 + f2 * f2 + f3 * f3;
    bf16x4 o;
    o[0] = (__bf16)(-2.f * f0); o[1] = (__bf16)(-2.f * f1);
    o[2] = (__bf16)(-2.f * f2); o[3] = (__bf16)(-2.f * f3);
    ofs[k] = o;

    float4 b = tf[k];
    __bf16 g0 = (__bf16)b.x, g1 = (__bf16)b.y, g2 = (__bf16)b.z, g3 = (__bf16)b.w;
    float e0 = (float)g0, e1 = (float)g1, e2 = (float)g2, e3 = (float)g3;
    fb += e0 * e0 + e1 * e1 + e2 * e2 + e3 * e3;
    bf16x4 o2;
    o2[0] = g0; o2[1] = g1; o2[2] = g2; o2[3] = g3;
    oft[k] = o2;
  }
  ((float*)(ws + FNS_OFF))[i] = fa;
  ((float*)(ws + FNT_OFF))[i] = fb;
  ((unsigned int*)(ws + MAXB_OFF))[i] = 0u;           // max(d2f) sentinel: 0
  ((unsigned int*)(ws + MINB_OFF))[i] = 0x7F7FFFFFu;  // FLT_MAX bits
}

// ---------------------------------------------------------------------------
// Phase 2: MFMA pairwise distances + masked row max/min. No LDS, no barriers.
// Wave = 32 rows (two 16x16 tiles) x 16-col steps. Block = 4 waves = 128 rows.
// Grid = (16 j-chunks of 512, 64 row-blocks).
// ---------------------------------------------------------------------------
__global__ __launch_bounds__(256, 4) void hcl_dist(char* __restrict__ ws) {
  const int lane = threadIdx.x & 63;
  const int wave = threadIdx.x >> 6;
  const int quad = lane >> 4;
  const int n = lane & 15;
  const int i0 = blockIdx.y * 128 + wave * 32;  // rows i0..i0+31
  const int j0 = blockIdx.x * 512;

  // A-side fragments (constant over the j loop)
  const bf16x8 afeat0 = *(const bf16x8*)(ws + FS2_OFF + (size_t)(i0 + n) * 64 + quad * 16);
  const bf16x8 afeat1 = *(const bf16x8*)(ws + FS2_OFF + (size_t)(i0 + 16 + n) * 64 + quad * 16);
  const bf16x8 apos0 = *(const bf16x8*)(ws + PSX_OFF + (size_t)(i0 + n) * 64 + quad * 16);
  const bf16x8 apos1 = *(const bf16x8*)(ws + PSX_OFF + (size_t)(i0 + 16 + n) * 64 + quad * 16);
  const f32x4 fa0 = *(const f32x4*)(ws + FNS_OFF + (size_t)(i0 + quad * 4) * 4);
  const f32x4 fa1 = *(const f32x4*)(ws + FNS_OFF + (size_t)(i0 + 16 + quad * 4) * 4);

  float maxv[8], minv[8];
#pragma unroll
  for (int r = 0; r < 8; ++r) {
    maxv[r] = -1.0f;
    minv[r] = FLT_MAX;
  }

#pragma unroll 2
  for (int s = 0; s < 32; ++s) {
    const int col = j0 + s * 16 + n;
    const bf16x8 bfeat = *(const bf16x8*)(ws + FT_OFF + (size_t)col * 64 + quad * 16);
    const bf16x8 bpos = *(const bf16x8*)(ws + PTX_OFF + (size_t)col * 64 + quad * 16);
    const float fb = *(const float*)(ws + FNT_OFF + (size_t)col * 4);

    f32x4 c0, c1, z;
    c0[0] = fa0[0] + fb; c0[1] = fa0[1] + fb; c0[2] = fa0[2] + fb; c0[3] = fa0[3] + fb;
    c1[0] = fa1[0] + fb; c1[1] = fa1[1] + fb; c1[2] = fa1[2] + fb; c1[3] = fa1[3] + fb;
    z[0] = 0.f; z[1] = 0.f; z[2] = 0.f; z[3] = 0.f;

    f32x4 d0 = __builtin_amdgcn_mfma_f32_16x16x32_bf16(afeat0, bfeat, c0, 0, 0, 0);
    f32x4 d1 = __builtin_amdgcn_mfma_f32_16x16x32_bf16(afeat1, bfeat, c1, 0, 0, 0);
    f32x4 u0 = __builtin_amdgcn_mfma_f32_16x16x32_bf16(apos0, bpos, z, 0, 0, 0);
    f32x4 u1 = __builtin_amdgcn_mfma_f32_16x16x32_bf16(apos1, bpos, z, 0, 0, 0);

#pragma unroll
    for (int r = 0; r < 4; ++r) {
      bool p0 = u0[r] < PRC, g0 = u0[r] > NRC;
      maxv[r] = fmaxf(maxv[r], p0 ? d0[r] : -1.0f);
      minv[r] = fminf(minv[r], g0 ? d0[r] : FLT_MAX);
      bool p1 = u1[r] < PRC, g1 = u1[r] > NRC;
      maxv[4 + r] = fmaxf(maxv[4 + r], p1 ? d1[r] : -1.0f);
      minv[4 + r] = fminf(minv[4 + r], g1 ? d1[r] : FLT_MAX);
    }
  }

  // reduce over the 16 lanes of each quad (cols), then atomic-merge per row
  unsigned int* maxb = (unsigned int*)(ws + MAXB_OFF);
  unsigned int* minb = (unsigned int*)(ws + MINB_OFF);
#pragma unroll
  for (int r = 0; r < 8; ++r) {
    float mx = maxv[r], mn = minv[r];
#pragma unroll
    for (int sh = 1; sh <= 8; sh <<= 1) {
      mx = fmaxf(mx, __shfl_xor(mx, sh, 64));
      mn = fminf(mn, __shfl_xor(mn, sh, 64));
    }
    if (n == 0) {
      int row = i0 + (r < 4 ? 0 : 16) + quad * 4 + (r & 3);
      atomicMax(maxb + row, __float_as_uint(fmaxf(mx, 0.f)));
      atomicMin(minb + row, __float_as_uint(fmaxf(mn, 0.f)));
    }
  }
}

// ---------------------------------------------------------------------------
// Phase 3: final loss reduction (single block)
// ---------------------------------------------------------------------------
__global__ __launch_bounds__(256) void hcl_loss(const char* __restrict__ ws,
                                               float* __restrict__ out) {
  int t = threadIdx.x;
  const float* maxb = (const float*)(ws + MAXB_OFF);
  const float* minb = (const float*)(ws + MINB_OFF);
  float sp = 0.f, sn = 0.f;
#pragma unroll 8
  for (int i = t; i < NN; i += 256) {
    float fp = sqrtf(maxb[i] + EPSF);
    float cn = sqrtf(minb[i] + EPSF);
    sp += fmaxf(fp - POS_TH, 0.f);
    sn += fmaxf(NEG_TH - cn, 0.f);
  }
  __shared__ float red[8];
#pragma unroll
  for (int s = 32; s >= 1; s >>= 1) {
    sp += __shfl_down(sp, s, 64);
    sn += __shfl_down(sn, s, 64);
  }
  int wid = t >> 6;
  if ((t & 63) == 0) {
    red[wid] = sp;
    red[4 + wid] = sn;
  }
  __syncthreads();
  if (t == 0) {
    float tsp = red[0] + red[1] + red[2] + red[3];
    float tsn = red[4] + red[5] + red[6] + red[7];
    out[0] = (tsp + tsn) * (1.0f / NN);
  }
}

// ---------------------------------------------------------------------------
extern "C" void kernel_launch(void* const* d_in, const int* in_sizes, int n_in,
                              void* d_out, int out_size, void* d_ws, size_t ws_size,
                              hipStream_t stream) {
  const float* src_pcd = (const float*)d_in[0];
  const float* tgt_pcd = (const float*)d_in[1];
  const float* src_feats = (const float*)d_in[2];
  const float* tgt_feats = (const float*)d_in[3];
  const int* corr = (const int*)d_in[4];
  const float* rot = (const float*)d_in[5];
  const float* trans = (const float*)d_in[6];
  float* out = (float*)d_out;
  char* ws = (char*)d_ws;

  hcl_prep<<<NN / 256, 256, 0, stream>>>(src_pcd, tgt_pcd, src_feats, tgt_feats, corr, rot,
                                         trans, ws);
  hcl_dist<<<dim3(16, 64), 256, 0, stream>>>(ws);
  hcl_loss<<<1, 256, 0, stream>>>(ws, out);
}

// Round 3
// 100.931 us; speedup vs baseline: 2.0152x; 1.0388x over previous
//
#include <hip/hip_runtime.h>
#include <math.h>
#include <float.h>

#define NN 8192

typedef __bf16 bf16x8 __attribute__((ext_vector_type(8)));
typedef float f32x4 __attribute__((ext_vector_type(4)));

constexpr float POS_R2 = 0.0375f * 0.0375f;
constexpr float NEG_R2 = 0.1f * 0.1f;
constexpr float EPSF = 1e-7f;
constexpr float PRC = POS_R2 - EPSF;  // pos:  d2p < PRC
constexpr float NRC = NEG_R2 - EPSF;  // neg:  d2p > NRC
constexpr float POS_TH = 0.1f;
constexpr float NEG_TH = 1.4f;

// ws byte offsets
#define FT_OFF 0                          // bf16 [NN][32] tgt feats
#define FS2_OFF (NN * 64)                 // bf16 [NN][32] -2 * src feats
#define PSX_OFF (2 * NN * 64)             // bf16 [NN][32] src pos ext (A side)
#define PTX_OFF (3 * NN * 64)             // bf16 [NN][32] tgt pos ext (B side)
#define FNS_OFF (4 * NN * 64)             // f32 [NN] src feat |.|^2 (rounded feats)
#define FNT_OFF (4 * NN * 64 + NN * 4)    // f32 [NN] tgt feat |.|^2
#define MAXB_OFF (4 * NN * 64 + 2 * NN * 4)
#define MINB_OFF (4 * NN * 64 + 3 * NN * 4)

// ---------------------------------------------------------------------------
// Phase 1: gather + transform + bf16 conversion + MFMA operand packing.
// 4 threads per correspondence: part p handles feat dims [8p, 8p+8);
// p==1 builds src position-ext row, p==2 builds tgt position-ext row.
// ---------------------------------------------------------------------------
__global__ __launch_bounds__(256) void hcl_prep(
    const float* __restrict__ src_pcd, const float* __restrict__ tgt_pcd,
    const float* __restrict__ src_feats, const float* __restrict__ tgt_feats,
    const int* __restrict__ corr, const float* __restrict__ rot,
    const float* __restrict__ trans, char* __restrict__ ws) {
  int t = blockIdx.x * 256 + threadIdx.x;  // 0..32767
  int i = t >> 2;
  int p = t & 3;
  int ci = corr[2 * i];
  int cj = corr[2 * i + 1];

  // ---- feats: this part's 8 dims = float4 chunks 2p, 2p+1 ----
  const float4* sf = (const float4*)(src_feats + (size_t)ci * 32);
  const float4* tf = (const float4*)(tgt_feats + (size_t)cj * 32);
  float na = 0.f, nb = 0.f;
  bf16x8 osrc, otgt;
#pragma unroll
  for (int h = 0; h < 2; ++h) {
    float4 a = sf[2 * p + h];
    __bf16 h0 = (__bf16)a.x, h1 = (__bf16)a.y, h2 = (__bf16)a.z, h3 = (__bf16)a.w;
    float f0 = (float)h0, f1 = (float)h1, f2 = (float)h2, f3 = (float)h3;
    na += f0 * f0 + f1 * f1 + f2 * f2 + f3 * f3;
    osrc[4 * h + 0] = (__bf16)(-2.f * f0);
    osrc[4 * h + 1] = (__bf16)(-2.f * f1);
    osrc[4 * h + 2] = (__bf16)(-2.f * f2);
    osrc[4 * h + 3] = (__bf16)(-2.f * f3);

    float4 b = tf[2 * p + h];
    __bf16 g0 = (__bf16)b.x, g1 = (__bf16)b.y, g2 = (__bf16)b.z, g3 = (__bf16)b.w;
    nb += (float)g0 * (float)g0 + (float)g1 * (float)g1 + (float)g2 * (float)g2 +
          (float)g3 * (float)g3;
    otgt[4 * h + 0] = g0;
    otgt[4 * h + 1] = g1;
    otgt[4 * h + 2] = g2;
    otgt[4 * h + 3] = g3;
  }
  *(bf16x8*)(ws + FS2_OFF + (size_t)i * 64 + p * 16) = osrc;
  *(bf16x8*)(ws + FT_OFF + (size_t)i * 64 + p * 16) = otgt;

  // reduce norms across the 4 parts (adjacent lanes)
  na += __shfl_xor(na, 1, 4);
  na += __shfl_xor(na, 2, 4);
  nb += __shfl_xor(nb, 1, 4);
  nb += __shfl_xor(nb, 2, 4);

  __bf16 one = (__bf16)1.0f, zero = (__bf16)0.0f;

  if (p == 0) {
    ((float*)(ws + FNS_OFF))[i] = na;
    ((float*)(ws + FNT_OFF))[i] = nb;
    ((unsigned int*)(ws + MAXB_OFF))[i] = 0u;           // max(d2f) sentinel
    ((unsigned int*)(ws + MINB_OFF))[i] = 0x7F7FFFFFu;  // FLT_MAX bits
  } else if (p == 1) {
    // src position-ext row: [ahi(3), ahi(3), alo(3), sahi, salo, 1, 1, 0...]
    float r00 = rot[0], r01 = rot[1], r02 = rot[2];
    float r10 = rot[3], r11 = rot[4], r12 = rot[5];
    float r20 = rot[6], r21 = rot[7], r22 = rot[8];
    float t0 = trans[0], t1 = trans[1], t2 = trans[2];
    float px = src_pcd[ci * 3 + 0], py = src_pcd[ci * 3 + 1], pz = src_pcd[ci * 3 + 2];
    float qx = r00 * px + r01 * py + r02 * pz + t0;
    float qy = r10 * px + r11 * py + r12 * pz + t1;
    float qz = r20 * px + r21 * py + r22 * pz + t2;
    float sa = qx * qx + qy * qy + qz * qz;
    __bf16 qhx = (__bf16)qx, qhy = (__bf16)qy, qhz = (__bf16)qz;
    __bf16 qlx = (__bf16)(qx - (float)qhx);
    __bf16 qly = (__bf16)(qy - (float)qhy);
    __bf16 qlz = (__bf16)(qz - (float)qhz);
    __bf16 sah = (__bf16)sa;
    __bf16 sal = (__bf16)(sa - (float)sah);
    bf16x8 v0, v1, vz;
    v0[0] = qhx; v0[1] = qhy; v0[2] = qhz; v0[3] = qhx; v0[4] = qhy; v0[5] = qhz;
    v0[6] = qlx; v0[7] = qly;
    v1[0] = qlz; v1[1] = sah; v1[2] = sal; v1[3] = one; v1[4] = one;
    v1[5] = zero; v1[6] = zero; v1[7] = zero;
#pragma unroll
    for (int k = 0; k < 8; ++k) vz[k] = zero;
    bf16x8* o = (bf16x8*)(ws + PSX_OFF + (size_t)i * 64);
    o[0] = v0; o[1] = v1; o[2] = vz; o[3] = vz;
  } else if (p == 2) {
    // tgt position-ext row: [-2bhi(3), -2blo(3), -2bhi(3), 1, 1, sbhi, sblo, 0...]
    float ux = tgt_pcd[cj * 3 + 0], uy = tgt_pcd[cj * 3 + 1], uz = tgt_pcd[cj * 3 + 2];
    float sb = ux * ux + uy * uy + uz * uz;
    __bf16 uhx = (__bf16)ux, uhy = (__bf16)uy, uhz = (__bf16)uz;
    __bf16 ulx = (__bf16)(ux - (float)uhx);
    __bf16 uly = (__bf16)(uy - (float)uhy);
    __bf16 ulz = (__bf16)(uz - (float)uhz);
    __bf16 sbh = (__bf16)sb;
    __bf16 sbl = (__bf16)(sb - (float)sbh);
    __bf16 m2hx = (__bf16)(-2.f * (float)uhx), m2hy = (__bf16)(-2.f * (float)uhy),
           m2hz = (__bf16)(-2.f * (float)uhz);
    __bf16 m2lx = (__bf16)(-2.f * (float)ulx), m2ly = (__bf16)(-2.f * (float)uly),
           m2lz = (__bf16)(-2.f * (float)ulz);
    bf16x8 w0, w1, wz;
    w0[0] = m2hx; w0[1] = m2hy; w0[2] = m2hz; w0[3] = m2lx; w0[4] = m2ly; w0[5] = m2lz;
    w0[6] = m2hx; w0[7] = m2hy;
    w1[0] = m2hz; w1[1] = one; w1[2] = one; w1[3] = sbh; w1[4] = sbl;
    w1[5] = zero; w1[6] = zero; w1[7] = zero;
#pragma unroll
    for (int k = 0; k < 8; ++k) wz[k] = zero;
    bf16x8* o = (bf16x8*)(ws + PTX_OFF + (size_t)i * 64);
    o[0] = w0; o[1] = w1; o[2] = wz; o[3] = wz;
  }
}

// ---------------------------------------------------------------------------
// Phase 2: MFMA pairwise distances + masked row max/min. No LDS, no barriers.
// Wave = 32 rows (two 16x16 tiles) x 16-col steps; 8 outer x 4 unrolled inner
// col-groups with immediate-offset loads (one pointer bump per 4 groups).
// Grid = (16 j-chunks of 512, 64 row-blocks), 4 blocks/CU resident.
// ---------------------------------------------------------------------------
__global__ __launch_bounds__(256, 4) void hcl_dist(char* __restrict__ ws) {
  const int lane = threadIdx.x & 63;
  const int wave = threadIdx.x >> 6;
  const int quad = lane >> 4;
  const int n = lane & 15;
  const int i0 = blockIdx.y * 128 + wave * 32;
  const int j0 = blockIdx.x * 512;
  const size_t aoff = (size_t)quad * 16;

  // A-side fragments (constant over the j loop)
  const bf16x8 afeat0 = *(const bf16x8*)(ws + FS2_OFF + (size_t)(i0 + n) * 64 + aoff);
  const bf16x8 afeat1 = *(const bf16x8*)(ws + FS2_OFF + (size_t)(i0 + 16 + n) * 64 + aoff);
  const bf16x8 apos0 = *(const bf16x8*)(ws + PSX_OFF + (size_t)(i0 + n) * 64 + aoff);
  const bf16x8 apos1 = *(const bf16x8*)(ws + PSX_OFF + (size_t)(i0 + 16 + n) * 64 + aoff);
  const f32x4 fa0 = *(const f32x4*)(ws + FNS_OFF + (size_t)(i0 + quad * 4) * 4);
  const f32x4 fa1 = *(const f32x4*)(ws + FNS_OFF + (size_t)(i0 + 16 + quad * 4) * 4);

  float maxv[8], minv[8];
#pragma unroll
  for (int r = 0; r < 8; ++r) {
    maxv[r] = -1.0f;
    minv[r] = FLT_MAX;
  }

  const char* pF = ws + FT_OFF + (size_t)(j0 + n) * 64 + aoff;
  const char* pP = ws + PTX_OFF + (size_t)(j0 + n) * 64 + aoff;
  const char* pN = ws + FNT_OFF + (size_t)(j0 + n) * 4;

  for (int s = 0; s < 8; ++s) {
#pragma unroll
    for (int u = 0; u < 4; ++u) {
      const bf16x8 bfeat = *(const bf16x8*)(pF + u * 1024);
      const bf16x8 bpos = *(const bf16x8*)(pP + u * 1024);
      const float fb = *(const float*)(pN + u * 64);

      f32x4 c0, c1, z;
      c0[0] = fa0[0] + fb; c0[1] = fa0[1] + fb; c0[2] = fa0[2] + fb; c0[3] = fa0[3] + fb;
      c1[0] = fa1[0] + fb; c1[1] = fa1[1] + fb; c1[2] = fa1[2] + fb; c1[3] = fa1[3] + fb;
      z[0] = 0.f; z[1] = 0.f; z[2] = 0.f; z[3] = 0.f;

      f32x4 d0 = __builtin_amdgcn_mfma_f32_16x16x32_bf16(afeat0, bfeat, c0, 0, 0, 0);
      f32x4 d1 = __builtin_amdgcn_mfma_f32_16x16x32_bf16(afeat1, bfeat, c1, 0, 0, 0);
      f32x4 u0 = __builtin_amdgcn_mfma_f32_16x16x32_bf16(apos0, bpos, z, 0, 0, 0);
      f32x4 u1 = __builtin_amdgcn_mfma_f32_16x16x32_bf16(apos1, bpos, z, 0, 0, 0);

#pragma unroll
      for (int r = 0; r < 4; ++r) {
        bool p0 = u0[r] < PRC, g0 = u0[r] > NRC;
        maxv[r] = fmaxf(maxv[r], p0 ? d0[r] : -1.0f);
        minv[r] = fminf(minv[r], g0 ? d0[r] : FLT_MAX);
        bool p1 = u1[r] < PRC, g1 = u1[r] > NRC;
        maxv[4 + r] = fmaxf(maxv[4 + r], p1 ? d1[r] : -1.0f);
        minv[4 + r] = fminf(minv[4 + r], g1 ? d1[r] : FLT_MAX);
      }
    }
    pF += 4096;
    pP += 4096;
    pN += 256;
  }

  // reduce over the 16 lanes of each quad (cols), then atomic-merge per row
  unsigned int* maxb = (unsigned int*)(ws + MAXB_OFF);
  unsigned int* minb = (unsigned int*)(ws + MINB_OFF);
#pragma unroll
  for (int r = 0; r < 8; ++r) {
    float mx = maxv[r], mn = minv[r];
#pragma unroll
    for (int sh = 1; sh <= 8; sh <<= 1) {
      mx = fmaxf(mx, __shfl_xor(mx, sh, 64));
      mn = fminf(mn, __shfl_xor(mn, sh, 64));
    }
    if (n == 0) {
      int row = i0 + (r < 4 ? 0 : 16) + quad * 4 + (r & 3);
      atomicMax(maxb + row, __float_as_uint(fmaxf(mx, 0.f)));
      atomicMin(minb + row, __float_as_uint(fmaxf(mn, 0.f)));
    }
  }
}

// ---------------------------------------------------------------------------
// Phase 3: final loss reduction (single block, float4 loads)
// ---------------------------------------------------------------------------
__global__ __launch_bounds__(256) void hcl_loss(const char* __restrict__ ws,
                                               float* __restrict__ out) {
  int t = threadIdx.x;
  const float4* maxb = (const float4*)(ws + MAXB_OFF);
  const float4* minb = (const float4*)(ws + MINB_OFF);
  float sp = 0.f, sn = 0.f;
#pragma unroll
  for (int k = 0; k < 8; ++k) {
    float4 mx = maxb[t + 256 * k];
    float4 mn = minb[t + 256 * k];
    sp += fmaxf(sqrtf(mx.x + EPSF) - POS_TH, 0.f) + fmaxf(sqrtf(mx.y + EPSF) - POS_TH, 0.f) +
          fmaxf(sqrtf(mx.z + EPSF) - POS_TH, 0.f) + fmaxf(sqrtf(mx.w + EPSF) - POS_TH, 0.f);
    sn += fmaxf(NEG_TH - sqrtf(mn.x + EPSF), 0.f) + fmaxf(NEG_TH - sqrtf(mn.y + EPSF), 0.f) +
          fmaxf(NEG_TH - sqrtf(mn.z + EPSF), 0.f) + fmaxf(NEG_TH - sqrtf(mn.w + EPSF), 0.f);
  }
  __shared__ float red[8];
#pragma unroll
  for (int s = 32; s >= 1; s >>= 1) {
    sp += __shfl_down(sp, s, 64);
    sn += __shfl_down(sn, s, 64);
  }
  int wid = t >> 6;
  if ((t & 63) == 0) {
    red[wid] = sp;
    red[4 + wid] = sn;
  }
  __syncthreads();
  if (t == 0) {
    float tsp = red[0] + red[1] + red[2] + red[3];
    float tsn = red[4] + red[5] + red[6] + red[7];
    out[0] = (tsp + tsn) * (1.0f / NN);
  }
}

// ---------------------------------------------------------------------------
extern "C" void kernel_launch(void* const* d_in, const int* in_sizes, int n_in,
                              void* d_out, int out_size, void* d_ws, size_t ws_size,
                              hipStream_t stream) {
  const float* src_pcd = (const float*)d_in[0];
  const float* tgt_pcd = (const float*)d_in[1];
  const float* src_feats = (const float*)d_in[2];
  const float* tgt_feats = (const float*)d_in[3];
  const int* corr = (const int*)d_in[4];
  const float* rot = (const float*)d_in[5];
  const float* trans = (const float*)d_in[6];
  float* out = (float*)d_out;
  char* ws = (char*)d_ws;

  hcl_prep<<<NN * 4 / 256, 256, 0, stream>>>(src_pcd, tgt_pcd, src_feats, tgt_feats, corr,
                                             rot, trans, ws);
  hcl_dist<<<dim3(16, 64), 256, 0, stream>>>(ws);
  hcl_loss<<<1, 256, 0, stream>>>(ws, out);
}